// Round 4
// baseline (652.422 us; speedup 1.0000x reference)
//
#include <hip/hip_runtime.h>
#include <hip/hip_bf16.h>
#include <math.h>

#define EMBED 1024
#define KD 64
#define NH 16
#define SEQ 2048
#define BATCH 4
#define BH (BATCH * NH)     // 64
#define NTOK ((size_t)BH * SEQ * KD)   // 8,388,608

typedef float4 f4;
typedef unsigned short u16;
typedef __attribute__((ext_vector_type(8))) short v8s;   // 8 bf16 (MFMA A/B frag)
typedef __attribute__((ext_vector_type(4))) float v4f;   // MFMA C/D frag

__device__ __forceinline__ u16 f2bf(float f) {
    unsigned u = __float_as_uint(f);
    unsigned r = (u + 0x7fffu + ((u >> 16) & 1u)) >> 16;
    return (u16)r;
}
__device__ __forceinline__ float bf2f(u16 h) {
    return __uint_as_float(((unsigned)h) << 16);
}

// async global->LDS, 16B/lane. LDS dest = wave-uniform base + lane*16.
__device__ __forceinline__ void gload_lds16(const void* g, void* l) {
    __builtin_amdgcn_global_load_lds(
        (const __attribute__((address_space(1))) unsigned int*)g,
        (__attribute__((address_space(3))) unsigned int*)l, 16, 0, 0);
}

// max-reduce over each 16-lane DPP row (lanes with same lane>>4), VALU-only:
// quad_perm xor1, quad_perm xor2, row_ror:4, row_ror:8.
__device__ __forceinline__ float dpp_max16(float v) {
    float t;
    t = __uint_as_float(__builtin_amdgcn_update_dpp(0, __float_as_uint(v), 0xB1, 0xF, 0xF, true));
    v = fmaxf(v, t);
    t = __uint_as_float(__builtin_amdgcn_update_dpp(0, __float_as_uint(v), 0x4E, 0xF, 0xF, true));
    v = fmaxf(v, t);
    t = __uint_as_float(__builtin_amdgcn_update_dpp(0, __float_as_uint(v), 0x124, 0xF, 0xF, true));
    v = fmaxf(v, t);
    t = __uint_as_float(__builtin_amdgcn_update_dpp(0, __float_as_uint(v), 0x128, 0xF, 0xF, true));
    v = fmaxf(v, t);
    return v;
}

// ------------------------------------------------------------------
// Converter 1: x fp32 -> xh/xl bf16 (hi/lo split), [8192][1024]
// ------------------------------------------------------------------
__global__ __launch_bounds__(256)
void convert_x_kernel(const float* __restrict__ x,
                      u16* __restrict__ xh, u16* __restrict__ xl)
{
    size_t i = ((size_t)blockIdx.x * 256 + threadIdx.x) * 4;
    f4 v = *(const f4*)(x + i);
    u16 h0 = f2bf(v.x), h1 = f2bf(v.y), h2 = f2bf(v.z), h3 = f2bf(v.w);
    u16 l0 = f2bf(v.x - bf2f(h0)), l1 = f2bf(v.y - bf2f(h1));
    u16 l2 = f2bf(v.z - bf2f(h2)), l3 = f2bf(v.w - bf2f(h3));
    uint2 H, L;
    H.x = (unsigned)h0 | ((unsigned)h1 << 16);
    H.y = (unsigned)h2 | ((unsigned)h3 << 16);
    L.x = (unsigned)l0 | ((unsigned)l1 << 16);
    L.y = (unsigned)l2 | ((unsigned)l3 << 16);
    *(uint2*)(xh + i) = H;
    *(uint2*)(xl + i) = L;
}

// ------------------------------------------------------------------
// Converter 2: wq/wk/wv [H][D][64] fp32 -> Wt hi/lo [3072][1024] bf16
// (transposed). Q scaled by 0.125*log2(e)  (exp2-domain softmax).
// ------------------------------------------------------------------
__global__ __launch_bounds__(256)
void convert_w_kernel(const float* __restrict__ wq, const float* __restrict__ wk,
                      const float* __restrict__ wv,
                      u16* __restrict__ Wth, u16* __restrict__ Wtl)
{
    int n = blockIdx.x;                       // 0..3071
    int mat = n >> 10, nin = n & 1023, h = nin >> 6, c = nin & 63;
    const float* __restrict__ ws = (mat == 0) ? wq : (mat == 1) ? wk : wv;
    float sc = (mat == 0) ? (0.125f * 1.4426950408889634f) : 1.0f;
    for (int d = threadIdx.x; d < EMBED; d += 256) {
        float f = ws[((size_t)h * EMBED + d) * KD + c] * sc;
        u16 hi = f2bf(f);
        u16 lo = f2bf(f - bf2f(hi));
        Wth[(size_t)n * EMBED + d] = hi;
        Wtl[(size_t)n * EMBED + d] = lo;
    }
}

// ------------------------------------------------------------------
// Converter 3: w [1024][1024] fp32 -> OWt hi/lo [n][k] bf16 (transposed)
// ------------------------------------------------------------------
__global__ __launch_bounds__(256)
void convert_ow_kernel(const float* __restrict__ w,
                       u16* __restrict__ OWth, u16* __restrict__ OWtl)
{
    int n = blockIdx.x;                       // 0..1023
    for (int k = threadIdx.x; k < EMBED; k += 256) {
        float f = w[(size_t)k * EMBED + n];
        u16 hi = f2bf(f);
        u16 lo = f2bf(f - bf2f(hi));
        OWth[(size_t)n * EMBED + k] = hi;
        OWtl[(size_t)n * EMBED + k] = lo;
    }
}

// ------------------------------------------------------------------
// Kernel: QKV projection, MFMA bf16 (unchanged from R3).
// ------------------------------------------------------------------
__global__ __launch_bounds__(256)
void qkv_mfma_kernel(const u16* __restrict__ xh, const u16* __restrict__ xl,
                     const u16* __restrict__ Wth, const u16* __restrict__ Wtl,
                     u16* __restrict__ Qhi, u16* __restrict__ Qlo,
                     u16* __restrict__ Khi, u16* __restrict__ Klo,
                     u16* __restrict__ Vt)
{
    __shared__ u16 sAh[128 * 64];
    __shared__ u16 sAl[128 * 64];
    __shared__ u16 sBh[128 * 64];
    __shared__ u16 sBl[128 * 64];
    const int tid = threadIdx.x;
    const int lane = tid & 63, wid = tid >> 6;
    const int lm = lane & 15, lq = lane >> 4;
    const int wm = wid & 1, wn = wid >> 1;
    const int m0 = blockIdx.y * 128;
    const int n0 = blockIdx.x * 128;
    const bool three = (n0 < 2048);

    v4f acc[4][4];
#pragma unroll
    for (int mt = 0; mt < 4; ++mt)
#pragma unroll
        for (int nt = 0; nt < 4; ++nt)
            acc[mt][nt] = (v4f){0.f, 0.f, 0.f, 0.f};

    const int srow = wid * 32 + (lane >> 3);
    const int sblk = (lane & 7) ^ (lane >> 3);

    for (int k0 = 0; k0 < EMBED; k0 += 64) {
        __syncthreads();
#pragma unroll
        for (int i = 0; i < 4; ++i) {
            int row = srow + i * 8;
            size_t gA = (((size_t)(m0 + row)) << 10) + k0 + sblk * 8;
            size_t gB = (((size_t)(n0 + row)) << 10) + k0 + sblk * 8;
            int lo = (wid * 32 + i * 8) * 128;
            gload_lds16((const char*)xh + gA * 2, (char*)sAh + lo);
            gload_lds16((const char*)Wth + gB * 2, (char*)sBh + lo);
            if (three) {
                gload_lds16((const char*)xl + gA * 2, (char*)sAl + lo);
                gload_lds16((const char*)Wtl + gB * 2, (char*)sBl + lo);
            }
        }
        asm volatile("s_waitcnt vmcnt(0)" ::: "memory");
        __syncthreads();

#pragma unroll
        for (int kks = 0; kks < 2; ++kks) {
            v8s ah[4], bh[4];
            const int ba = ((kks * 4 + lq) ^ (lm & 7)) * 8;
#pragma unroll
            for (int t = 0; t < 4; ++t) {
                int ra = wm * 64 + t * 16 + lm;
                int rb = wn * 64 + t * 16 + lm;
                ah[t] = *(const v8s*)&sAh[ra * 64 + ba];
                bh[t] = *(const v8s*)&sBh[rb * 64 + ba];
            }
            if (three) {
                v8s al[4], bl[4];
#pragma unroll
                for (int t = 0; t < 4; ++t) {
                    int ra = wm * 64 + t * 16 + lm;
                    int rb = wn * 64 + t * 16 + lm;
                    al[t] = *(const v8s*)&sAl[ra * 64 + ba];
                    bl[t] = *(const v8s*)&sBl[rb * 64 + ba];
                }
#pragma unroll
                for (int mt = 0; mt < 4; ++mt)
#pragma unroll
                    for (int nt = 0; nt < 4; ++nt) {
                        acc[mt][nt] = __builtin_amdgcn_mfma_f32_16x16x32_bf16(ah[mt], bh[nt], acc[mt][nt], 0, 0, 0);
                        acc[mt][nt] = __builtin_amdgcn_mfma_f32_16x16x32_bf16(ah[mt], bl[nt], acc[mt][nt], 0, 0, 0);
                        acc[mt][nt] = __builtin_amdgcn_mfma_f32_16x16x32_bf16(al[mt], bh[nt], acc[mt][nt], 0, 0, 0);
                    }
            } else {
#pragma unroll
                for (int mt = 0; mt < 4; ++mt)
#pragma unroll
                    for (int nt = 0; nt < 4; ++nt)
                        acc[mt][nt] = __builtin_amdgcn_mfma_f32_16x16x32_bf16(ah[mt], bh[nt], acc[mt][nt], 0, 0, 0);
            }
        }
    }

    const int mrow0 = m0 + wm * 64;
    const int ncol0 = n0 + wn * 64;
    if (!three) {
#pragma unroll
        for (int mt = 0; mt < 4; ++mt) {
            int sbase = mrow0 + mt * 16 + lq * 4;
            int bb = sbase >> 11, s = sbase & 2047;
#pragma unroll
            for (int nt = 0; nt < 4; ++nt) {
                int nin = (ncol0 + nt * 16 + lm) & 1023;
                int h = nin >> 6, cc = nin & 63;
                int bh_ = bb * NH + h;
                size_t a = ((size_t)bh_ * KD + cc) * SEQ
                         + (size_t)(((((s >> 3) ^ (cc & 7)) << 3)) | (s & 7));
                uint2 u;
                u.x = (unsigned)f2bf(acc[mt][nt][0]) | ((unsigned)f2bf(acc[mt][nt][1]) << 16);
                u.y = (unsigned)f2bf(acc[mt][nt][2]) | ((unsigned)f2bf(acc[mt][nt][3]) << 16);
                *(uint2*)(Vt + a) = u;
            }
        }
    } else {
        const bool isQ = (n0 < 1024);
#pragma unroll
        for (int mt = 0; mt < 4; ++mt) {
            int sbase = mrow0 + mt * 16 + lq * 4;
            int bb = sbase >> 11, sB = sbase & 2047;
#pragma unroll
            for (int nt = 0; nt < 4; ++nt) {
                int nin = (ncol0 + nt * 16 + lm) & 1023;
                int h = nin >> 6, cc = nin & 63;
                int bh_ = bb * NH + h;
#pragma unroll
                for (int r = 0; r < 4; ++r) {
                    int s = sB + r;
                    float f = acc[mt][nt][r];
                    u16 hi = f2bf(f);
                    u16 lo = f2bf(f - bf2f(hi));
                    if (isQ) {
                        size_t a = ((size_t)bh_ * SEQ + s) * KD + cc;
                        Qhi[a] = hi;
                        Qlo[a] = lo;
                    } else {
                        int ccp = ((((cc >> 3) ^ (s & 7)) << 3) | (cc & 7));
                        size_t a = ((size_t)bh_ * SEQ + s) * KD + ccp;
                        Khi[a] = hi;
                        Klo[a] = lo;
                    }
                }
            }
        }
    }
}

// ------------------------------------------------------------------
// Kernel: flash attention, MFMA bf16, exp2-domain online softmax.
// Block = 128 threads = 2 waves; 64 q-rows per wave (128/block).
// l via ones-column MFMA; max via DPP; K/V staged with global_load_lds.
// ------------------------------------------------------------------
#define PSTRIDE 72   // u16; 144B rows = 9 x 16B (16B-aligned, 2-way banks)

__global__ __launch_bounds__(128, 2)
void attn_kernel(const u16* __restrict__ Qhi, const u16* __restrict__ Qlo,
                 const u16* __restrict__ Khi, const u16* __restrict__ Klo,
                 const u16* __restrict__ Vt,  u16* __restrict__ headsb)
{
    __shared__ u16 sKhi[64 * 64];
    __shared__ u16 sKlo[64 * 64];
    __shared__ u16 sVt[64 * 64];
    __shared__ u16 sPs[128 * PSTRIDE];

    const int tid = threadIdx.x;
    const int lane = tid & 63, wid = tid >> 6;
    const int lm = lane & 15, lq = lane >> 4;
    const int q0 = blockIdx.x * 128;
    const int bh = blockIdx.y;
    const int bb = bh >> 4, h = bh & 15;

    // Q fragments resident: rows q0 + wid*64 + mt*16 + lm
    v8s qh[4][2], ql[4][2];
#pragma unroll
    for (int mt = 0; mt < 4; ++mt)
#pragma unroll
        for (int kk = 0; kk < 2; ++kk) {
            size_t g = ((size_t)bh * SEQ + q0 + wid * 64 + mt * 16 + lm) * KD
                     + kk * 32 + lq * 8;
            qh[mt][kk] = *(const v8s*)(Qhi + g);
            ql[mt][kk] = *(const v8s*)(Qlo + g);
        }

    v8s vones;
#pragma unroll
    for (int i = 0; i < 8; ++i) vones[i] = (short)0x3F80;   // bf16 1.0

    v4f ctx[4][4], lcol[4];
    float mrun[4][4];
#pragma unroll
    for (int mt = 0; mt < 4; ++mt) {
        lcol[mt] = (v4f){0.f, 0.f, 0.f, 0.f};
#pragma unroll
        for (int r = 0; r < 4; ++r) mrun[mt][r] = -INFINITY;
#pragma unroll
        for (int nt = 0; nt < 4; ++nt)
            ctx[mt][nt] = (v4f){0.f, 0.f, 0.f, 0.f};
    }

    const size_t kbase = (size_t)bh * SEQ * KD;

    for (int t0 = 0; t0 < SEQ; t0 += 64) {
        __syncthreads();
        // ---- stage Khi/Klo (8KB each, contiguous): wave covers half
        {
            const char* gk1 = (const char*)(Khi + kbase + (size_t)t0 * KD);
            const char* gk2 = (const char*)(Klo + kbase + (size_t)t0 * KD);
#pragma unroll
            for (int i = 0; i < 4; ++i) {
                int o = wid * 4096 + i * 1024;
                gload_lds16(gk1 + o + lane * 16, (char*)sKhi + o);
                gload_lds16(gk2 + o + lane * 16, (char*)sKlo + o);
            }
        }
        // ---- stage Vt rows (128B per hd row): 8 rows per wave-inst
#pragma unroll
        for (int i = 0; i < 4; ++i) {
            int row = wid * 32 + i * 8;
            const char* gv = (const char*)(Vt + ((size_t)bh * KD + row + (lane >> 3)) * SEQ + t0)
                           + (lane & 7) * 16;
            gload_lds16(gv, (char*)sVt + row * 128);
        }
        asm volatile("s_waitcnt vmcnt(0)" ::: "memory");
        __syncthreads();

        // ---- QK^T: 3-term split-bf16, fp32 accum
        v4f sc[4][4];
#pragma unroll
        for (int mt = 0; mt < 4; ++mt)
#pragma unroll
            for (int nt = 0; nt < 4; ++nt)
                sc[mt][nt] = (v4f){0.f, 0.f, 0.f, 0.f};
#pragma unroll
        for (int kk = 0; kk < 2; ++kk) {
#pragma unroll
            for (int nt = 0; nt < 4; ++nt) {
                int key = nt * 16 + lm;
                int blk = (kk * 4 + lq) ^ (key & 7);
                v8s bh16 = *(const v8s*)&sKhi[key * 64 + blk * 8];
                v8s bl16 = *(const v8s*)&sKlo[key * 64 + blk * 8];
#pragma unroll
                for (int mt = 0; mt < 4; ++mt) {
                    sc[mt][nt] = __builtin_amdgcn_mfma_f32_16x16x32_bf16(qh[mt][kk], bh16, sc[mt][nt], 0, 0, 0);
                    sc[mt][nt] = __builtin_amdgcn_mfma_f32_16x16x32_bf16(qh[mt][kk], bl16, sc[mt][nt], 0, 0, 0);
                    sc[mt][nt] = __builtin_amdgcn_mfma_f32_16x16x32_bf16(ql[mt][kk], bh16, sc[mt][nt], 0, 0, 0);
                }
            }
        }

        // ---- online softmax (base-2). C-layout: col=nt*16+lm, row=mt*16+lq*4+r
#pragma unroll
        for (int mt = 0; mt < 4; ++mt) {
#pragma unroll
            for (int r = 0; r < 4; ++r) {
                float v0 = sc[mt][0][r], v1 = sc[mt][1][r];
                float v2 = sc[mt][2][r], v3 = sc[mt][3][r];
                float mx = fmaxf(fmaxf(v0, v1), fmaxf(v2, v3));
                mx = dpp_max16(mx);
                float mold = mrun[mt][r];
                float mnew = fmaxf(mold, mx);
                float alpha = __builtin_amdgcn_exp2f(mold - mnew);
                mrun[mt][r] = mnew;
                float p0 = __builtin_amdgcn_exp2f(v0 - mnew);
                float p1 = __builtin_amdgcn_exp2f(v1 - mnew);
                float p2 = __builtin_amdgcn_exp2f(v2 - mnew);
                float p3 = __builtin_amdgcn_exp2f(v3 - mnew);
                lcol[mt][r] *= alpha;
#pragma unroll
                for (int nt = 0; nt < 4; ++nt)
                    ctx[mt][nt][r] *= alpha;
                int row = wid * 64 + mt * 16 + lq * 4 + r;
                sPs[row * PSTRIDE +  0 + lm] = f2bf(p0);
                sPs[row * PSTRIDE + 16 + lm] = f2bf(p1);
                sPs[row * PSTRIDE + 32 + lm] = f2bf(p2);
                sPs[row * PSTRIDE + 48 + lm] = f2bf(p3);
            }
        }
        // same-wave ds_write -> ds_read (compiler inserts lgkm wait)

        // ---- PV (+ ones column accumulates l)
#pragma unroll
        for (int kk2 = 0; kk2 < 2; ++kk2) {
            v8s a[4];
#pragma unroll
            for (int mt = 0; mt < 4; ++mt)
                a[mt] = *(const v8s*)&sPs[(wid * 64 + mt * 16 + lm) * PSTRIDE + kk2 * 32 + lq * 8];
#pragma unroll
            for (int nt = 0; nt < 4; ++nt) {
                int hd = nt * 16 + lm;
                int blk = (kk2 * 4 + lq) ^ (hd & 7);
                v8s b = *(const v8s*)&sVt[hd * 64 + blk * 8];
#pragma unroll
                for (int mt = 0; mt < 4; ++mt)
                    ctx[mt][nt] = __builtin_amdgcn_mfma_f32_16x16x32_bf16(a[mt], b, ctx[mt][nt], 0, 0, 0);
            }
#pragma unroll
            for (int mt = 0; mt < 4; ++mt)
                lcol[mt] = __builtin_amdgcn_mfma_f32_16x16x32_bf16(a[mt], vones, lcol[mt], 0, 0, 0);
        }
    }

    // ---- epilogue: heads[bb][row][h*64+hd] = ctx / l (bf16)
#pragma unroll
    for (int mt = 0; mt < 4; ++mt)
#pragma unroll
        for (int r = 0; r < 4; ++r) {
            int row = q0 + wid * 64 + mt * 16 + lq * 4 + r;
            float inv = 1.0f / lcol[mt][r];
            u16* dst = headsb + ((size_t)bb * SEQ + row) * EMBED + h * KD;
#pragma unroll
            for (int nt = 0; nt < 4; ++nt)
                dst[nt * 16 + lm] = f2bf(ctx[mt][nt][r] * inv);
        }
}

// ------------------------------------------------------------------
// Kernel: output projection, MFMA bf16 2-term (unchanged from R3).
// ------------------------------------------------------------------
__global__ __launch_bounds__(256)
void out_mfma_kernel(const u16* __restrict__ headsb,
                     const u16* __restrict__ OWth, const u16* __restrict__ OWtl,
                     float* __restrict__ out)
{
    __shared__ u16 sA[128 * 64];
    __shared__ u16 sBh[128 * 64];
    __shared__ u16 sBl[128 * 64];
    const int tid = threadIdx.x;
    const int lane = tid & 63, wid = tid >> 6;
    const int lm = lane & 15, lq = lane >> 4;
    const int wm = wid & 1, wn = wid >> 1;
    const int m0 = blockIdx.y * 128;
    const int n0 = blockIdx.x * 128;

    v4f acc[4][4];
#pragma unroll
    for (int mt = 0; mt < 4; ++mt)
#pragma unroll
        for (int nt = 0; nt < 4; ++nt)
            acc[mt][nt] = (v4f){0.f, 0.f, 0.f, 0.f};

    const int srow = wid * 32 + (lane >> 3);
    const int sblk = (lane & 7) ^ (lane >> 3);

    for (int k0 = 0; k0 < EMBED; k0 += 64) {
        __syncthreads();
#pragma unroll
        for (int i = 0; i < 4; ++i) {
            int row = srow + i * 8;
            size_t gA = (((size_t)(m0 + row)) << 10) + k0 + sblk * 8;
            size_t gB = (((size_t)(n0 + row)) << 10) + k0 + sblk * 8;
            int lo = (wid * 32 + i * 8) * 128;
            gload_lds16((const char*)headsb + gA * 2, (char*)sA + lo);
            gload_lds16((const char*)OWth + gB * 2, (char*)sBh + lo);
            gload_lds16((const char*)OWtl + gB * 2, (char*)sBl + lo);
        }
        asm volatile("s_waitcnt vmcnt(0)" ::: "memory");
        __syncthreads();

#pragma unroll
        for (int kks = 0; kks < 2; ++kks) {
            const int ba = ((kks * 4 + lq) ^ (lm & 7)) * 8;
            v8s ah[4], bh[4], bl[4];
#pragma unroll
            for (int t = 0; t < 4; ++t) {
                int ra = wm * 64 + t * 16 + lm;
                int rb = wn * 64 + t * 16 + lm;
                ah[t] = *(const v8s*)&sA[ra * 64 + ba];
                bh[t] = *(const v8s*)&sBh[rb * 64 + ba];
                bl[t] = *(const v8s*)&sBl[rb * 64 + ba];
            }
#pragma unroll
            for (int mt = 0; mt < 4; ++mt)
#pragma unroll
                for (int nt = 0; nt < 4; ++nt) {
                    acc[mt][nt] = __builtin_amdgcn_mfma_f32_16x16x32_bf16(ah[mt], bh[nt], acc[mt][nt], 0, 0, 0);
                    acc[mt][nt] = __builtin_amdgcn_mfma_f32_16x16x32_bf16(ah[mt], bl[nt], acc[mt][nt], 0, 0, 0);
                }
        }
    }

    const int mrow0 = m0 + wm * 64;
    const int ncol0 = n0 + wn * 64;
#pragma unroll
    for (int mt = 0; mt < 4; ++mt) {
        int sbase = mrow0 + mt * 16 + lq * 4;
#pragma unroll
        for (int nt = 0; nt < 4; ++nt) {
            int n = ncol0 + nt * 16 + lm;
#pragma unroll
            for (int r = 0; r < 4; ++r)
                out[(size_t)(sbase + r) * EMBED + n] = acc[mt][nt][r];
        }
    }
}

// ------------------------------------------------------------------
extern "C" void kernel_launch(void* const* d_in, const int* in_sizes, int n_in,
                              void* d_out, int out_size, void* d_ws, size_t ws_size,
                              hipStream_t stream) {
    const float* x  = (const float*)d_in[0];
    const float* wq = (const float*)d_in[1];
    const float* wk = (const float*)d_in[2];
    const float* wv = (const float*)d_in[3];
    const float* w  = (const float*)d_in[4];
    float* out = (float*)d_out;

    u16* Qhi = (u16*)d_ws;
    u16* Qlo = Qhi + NTOK;
    u16* Khi = Qlo + NTOK;
    u16* Klo = Khi + NTOK;
    u16* Vt  = Klo + NTOK;
    u16* xh  = Vt + NTOK;                 // [8192][1024]
    u16* xl  = xh + NTOK;
    u16* Wth = xl + NTOK;                 // [3072][1024]
    u16* Wtl = Wth + (size_t)3072 * 1024;
    u16* OWth = Wtl + (size_t)3072 * 1024;  // [1024][1024]
    u16* OWtl = OWth + (size_t)1024 * 1024;
    u16* headsb = xh;                     // alias: xh dead after qkv_mfma

    convert_x_kernel<<<8192, 256, 0, stream>>>(x, xh, xl);
    convert_w_kernel<<<3072, 256, 0, stream>>>(wq, wk, wv, Wth, Wtl);
    convert_ow_kernel<<<1024, 256, 0, stream>>>(w, OWth, OWtl);

    dim3 g1(24, 64);
    qkv_mfma_kernel<<<g1, 256, 0, stream>>>(xh, xl, Wth, Wtl, Qhi, Qlo, Khi, Klo, Vt);

    dim3 g2(SEQ / 128, BH);   // 16 x 64, 128-thread blocks
    attn_kernel<<<g2, 128, 0, stream>>>(Qhi, Qlo, Khi, Klo, Vt, headsb);

    dim3 g3(8, 64);
    out_mfma_kernel<<<g3, 256, 0, stream>>>(headsb, OWth, OWtl, out);
}

// Round 5
// 500.635 us; speedup vs baseline: 1.3032x; 1.3032x over previous
//
#include <hip/hip_runtime.h>
#include <hip/hip_bf16.h>
#include <math.h>

#define EMBED 1024
#define KD 64
#define NH 16
#define SEQ 2048
#define BATCH 4
#define BH (BATCH * NH)     // 64
#define NTOK ((size_t)BH * SEQ * KD)   // 8,388,608

typedef float4 f4;
typedef unsigned short u16;
typedef __attribute__((ext_vector_type(8))) short v8s;   // 8 bf16 (MFMA A/B frag)
typedef __attribute__((ext_vector_type(4))) float v4f;   // MFMA C/D frag

__device__ __forceinline__ u16 f2bf(float f) {
    unsigned u = __float_as_uint(f);
    unsigned r = (u + 0x7fffu + ((u >> 16) & 1u)) >> 16;
    return (u16)r;
}
__device__ __forceinline__ float bf2f(u16 h) {
    return __uint_as_float(((unsigned)h) << 16);
}

// async global->LDS, 16B/lane. LDS dest = wave-uniform base + lane*16.
__device__ __forceinline__ void gload_lds16(const void* g, void* l) {
    __builtin_amdgcn_global_load_lds(
        (const __attribute__((address_space(1))) unsigned int*)g,
        (__attribute__((address_space(3))) unsigned int*)l, 16, 0, 0);
}

// max-reduce over each 16-lane DPP row, VALU-only (verified R4):
__device__ __forceinline__ float dpp_max16(float v) {
    float t;
    t = __uint_as_float(__builtin_amdgcn_update_dpp(0, __float_as_uint(v), 0xB1, 0xF, 0xF, true));
    v = fmaxf(v, t);
    t = __uint_as_float(__builtin_amdgcn_update_dpp(0, __float_as_uint(v), 0x4E, 0xF, 0xF, true));
    v = fmaxf(v, t);
    t = __uint_as_float(__builtin_amdgcn_update_dpp(0, __float_as_uint(v), 0x124, 0xF, 0xF, true));
    v = fmaxf(v, t);
    t = __uint_as_float(__builtin_amdgcn_update_dpp(0, __float_as_uint(v), 0x128, 0xF, 0xF, true));
    v = fmaxf(v, t);
    return v;
}

// ------------------------------------------------------------------
// Converter 1: x fp32 -> xh/xl bf16 (hi/lo split), [8192][1024]
// ------------------------------------------------------------------
__global__ __launch_bounds__(256)
void convert_x_kernel(const float* __restrict__ x,
                      u16* __restrict__ xh, u16* __restrict__ xl)
{
    size_t i = ((size_t)blockIdx.x * 256 + threadIdx.x) * 4;
    f4 v = *(const f4*)(x + i);
    u16 h0 = f2bf(v.x), h1 = f2bf(v.y), h2 = f2bf(v.z), h3 = f2bf(v.w);
    u16 l0 = f2bf(v.x - bf2f(h0)), l1 = f2bf(v.y - bf2f(h1));
    u16 l2 = f2bf(v.z - bf2f(h2)), l3 = f2bf(v.w - bf2f(h3));
    uint2 H, L;
    H.x = (unsigned)h0 | ((unsigned)h1 << 16);
    H.y = (unsigned)h2 | ((unsigned)h3 << 16);
    L.x = (unsigned)l0 | ((unsigned)l1 << 16);
    L.y = (unsigned)l2 | ((unsigned)l3 << 16);
    *(uint2*)(xh + i) = H;
    *(uint2*)(xl + i) = L;
}

// ------------------------------------------------------------------
// Converter 2: wq/wk/wv [H][D][64] fp32 -> Wt hi/lo [3072][1024] bf16
// (transposed). Q scaled by 0.125*log2(e)  (exp2-domain softmax).
// ------------------------------------------------------------------
__global__ __launch_bounds__(256)
void convert_w_kernel(const float* __restrict__ wq, const float* __restrict__ wk,
                      const float* __restrict__ wv,
                      u16* __restrict__ Wth, u16* __restrict__ Wtl)
{
    int n = blockIdx.x;                       // 0..3071
    int mat = n >> 10, nin = n & 1023, h = nin >> 6, c = nin & 63;
    const float* __restrict__ ws = (mat == 0) ? wq : (mat == 1) ? wk : wv;
    float sc = (mat == 0) ? (0.125f * 1.4426950408889634f) : 1.0f;
    for (int d = threadIdx.x; d < EMBED; d += 256) {
        float f = ws[((size_t)h * EMBED + d) * KD + c] * sc;
        u16 hi = f2bf(f);
        u16 lo = f2bf(f - bf2f(hi));
        Wth[(size_t)n * EMBED + d] = hi;
        Wtl[(size_t)n * EMBED + d] = lo;
    }
}

// ------------------------------------------------------------------
// Converter 3: w [1024][1024] fp32 -> OWt hi/lo [n][k] bf16 (transposed)
// ------------------------------------------------------------------
__global__ __launch_bounds__(256)
void convert_ow_kernel(const float* __restrict__ w,
                       u16* __restrict__ OWth, u16* __restrict__ OWtl)
{
    int n = blockIdx.x;                       // 0..1023
    for (int k = threadIdx.x; k < EMBED; k += 256) {
        float f = w[(size_t)k * EMBED + n];
        u16 hi = f2bf(f);
        u16 lo = f2bf(f - bf2f(hi));
        OWth[(size_t)n * EMBED + k] = hi;
        OWtl[(size_t)n * EMBED + k] = lo;
    }
}

// ------------------------------------------------------------------
// Kernel: QKV projection, MFMA bf16 (unchanged from R3).
// ------------------------------------------------------------------
__global__ __launch_bounds__(256)
void qkv_mfma_kernel(const u16* __restrict__ xh, const u16* __restrict__ xl,
                     const u16* __restrict__ Wth, const u16* __restrict__ Wtl,
                     u16* __restrict__ Qhi, u16* __restrict__ Qlo,
                     u16* __restrict__ Khi, u16* __restrict__ Klo,
                     u16* __restrict__ Vt)
{
    __shared__ u16 sAh[128 * 64];
    __shared__ u16 sAl[128 * 64];
    __shared__ u16 sBh[128 * 64];
    __shared__ u16 sBl[128 * 64];
    const int tid = threadIdx.x;
    const int lane = tid & 63, wid = tid >> 6;
    const int lm = lane & 15, lq = lane >> 4;
    const int wm = wid & 1, wn = wid >> 1;
    const int m0 = blockIdx.y * 128;
    const int n0 = blockIdx.x * 128;
    const bool three = (n0 < 2048);

    v4f acc[4][4];
#pragma unroll
    for (int mt = 0; mt < 4; ++mt)
#pragma unroll
        for (int nt = 0; nt < 4; ++nt)
            acc[mt][nt] = (v4f){0.f, 0.f, 0.f, 0.f};

    const int srow = wid * 32 + (lane >> 3);
    const int sblk = (lane & 7) ^ (lane >> 3);

    for (int k0 = 0; k0 < EMBED; k0 += 64) {
        __syncthreads();
#pragma unroll
        for (int i = 0; i < 4; ++i) {
            int row = srow + i * 8;
            size_t gA = (((size_t)(m0 + row)) << 10) + k0 + sblk * 8;
            size_t gB = (((size_t)(n0 + row)) << 10) + k0 + sblk * 8;
            int lo = (wid * 32 + i * 8) * 128;
            gload_lds16((const char*)xh + gA * 2, (char*)sAh + lo);
            gload_lds16((const char*)Wth + gB * 2, (char*)sBh + lo);
            if (three) {
                gload_lds16((const char*)xl + gA * 2, (char*)sAl + lo);
                gload_lds16((const char*)Wtl + gB * 2, (char*)sBl + lo);
            }
        }
        asm volatile("s_waitcnt vmcnt(0)" ::: "memory");
        __syncthreads();

#pragma unroll
        for (int kks = 0; kks < 2; ++kks) {
            v8s ah[4], bh[4];
            const int ba = ((kks * 4 + lq) ^ (lm & 7)) * 8;
#pragma unroll
            for (int t = 0; t < 4; ++t) {
                int ra = wm * 64 + t * 16 + lm;
                int rb = wn * 64 + t * 16 + lm;
                ah[t] = *(const v8s*)&sAh[ra * 64 + ba];
                bh[t] = *(const v8s*)&sBh[rb * 64 + ba];
            }
            if (three) {
                v8s al[4], bl[4];
#pragma unroll
                for (int t = 0; t < 4; ++t) {
                    int ra = wm * 64 + t * 16 + lm;
                    int rb = wn * 64 + t * 16 + lm;
                    al[t] = *(const v8s*)&sAl[ra * 64 + ba];
                    bl[t] = *(const v8s*)&sBl[rb * 64 + ba];
                }
#pragma unroll
                for (int mt = 0; mt < 4; ++mt)
#pragma unroll
                    for (int nt = 0; nt < 4; ++nt) {
                        acc[mt][nt] = __builtin_amdgcn_mfma_f32_16x16x32_bf16(ah[mt], bh[nt], acc[mt][nt], 0, 0, 0);
                        acc[mt][nt] = __builtin_amdgcn_mfma_f32_16x16x32_bf16(ah[mt], bl[nt], acc[mt][nt], 0, 0, 0);
                        acc[mt][nt] = __builtin_amdgcn_mfma_f32_16x16x32_bf16(al[mt], bh[nt], acc[mt][nt], 0, 0, 0);
                    }
            } else {
#pragma unroll
                for (int mt = 0; mt < 4; ++mt)
#pragma unroll
                    for (int nt = 0; nt < 4; ++nt)
                        acc[mt][nt] = __builtin_amdgcn_mfma_f32_16x16x32_bf16(ah[mt], bh[nt], acc[mt][nt], 0, 0, 0);
            }
        }
    }

    const int mrow0 = m0 + wm * 64;
    const int ncol0 = n0 + wn * 64;
    if (!three) {
#pragma unroll
        for (int mt = 0; mt < 4; ++mt) {
            int sbase = mrow0 + mt * 16 + lq * 4;
            int bb = sbase >> 11, s = sbase & 2047;
#pragma unroll
            for (int nt = 0; nt < 4; ++nt) {
                int nin = (ncol0 + nt * 16 + lm) & 1023;
                int h = nin >> 6, cc = nin & 63;
                int bh_ = bb * NH + h;
                size_t a = ((size_t)bh_ * KD + cc) * SEQ
                         + (size_t)(((((s >> 3) ^ (cc & 7)) << 3)) | (s & 7));
                uint2 u;
                u.x = (unsigned)f2bf(acc[mt][nt][0]) | ((unsigned)f2bf(acc[mt][nt][1]) << 16);
                u.y = (unsigned)f2bf(acc[mt][nt][2]) | ((unsigned)f2bf(acc[mt][nt][3]) << 16);
                *(uint2*)(Vt + a) = u;
            }
        }
    } else {
        const bool isQ = (n0 < 1024);
#pragma unroll
        for (int mt = 0; mt < 4; ++mt) {
            int sbase = mrow0 + mt * 16 + lq * 4;
            int bb = sbase >> 11, sB = sbase & 2047;
#pragma unroll
            for (int nt = 0; nt < 4; ++nt) {
                int nin = (ncol0 + nt * 16 + lm) & 1023;
                int h = nin >> 6, cc = nin & 63;
                int bh_ = bb * NH + h;
#pragma unroll
                for (int r = 0; r < 4; ++r) {
                    int s = sB + r;
                    float f = acc[mt][nt][r];
                    u16 hi = f2bf(f);
                    u16 lo = f2bf(f - bf2f(hi));
                    if (isQ) {
                        size_t a = ((size_t)bh_ * SEQ + s) * KD + cc;
                        Qhi[a] = hi;
                        Qlo[a] = lo;
                    } else {
                        int ccp = ((((cc >> 3) ^ (s & 7)) << 3) | (cc & 7));
                        size_t a = ((size_t)bh_ * SEQ + s) * KD + ccp;
                        Khi[a] = hi;
                        Klo[a] = lo;
                    }
                }
            }
        }
    }
}

// ------------------------------------------------------------------
// Kernel: flash attention. R3 shape (256 thr / 4 waves / 32 q-rows per
// wave / 3 blocks per CU) + R4's pipe-relief mods: ones-MFMA row-sum,
// DPP max, exp2-domain softmax, global_load_lds V staging.
// ------------------------------------------------------------------
#define PSTRIDE 72   // u16; 144B rows (16B-aligned; PV reads 2-way banks = free)

__global__ __launch_bounds__(256)
void attn_kernel(const u16* __restrict__ Qhi, const u16* __restrict__ Qlo,
                 const u16* __restrict__ Khi, const u16* __restrict__ Klo,
                 const u16* __restrict__ Vt,  u16* __restrict__ headsb)
{
    __shared__ u16 sKhi[64 * 64];
    __shared__ u16 sKlo[64 * 64];
    __shared__ u16 sVt[64 * 64];
    __shared__ u16 sPs[128 * PSTRIDE];

    const int tid = threadIdx.x;
    const int lane = tid & 63, wid = tid >> 6;
    const int lm = lane & 15, lq = lane >> 4;
    const int q0 = blockIdx.x * 128;
    const int bh = blockIdx.y;
    const int bb = bh >> 4, h = bh & 15;

    // Q fragments resident: rows q0 + wid*32 + mt*16 + lm
    v8s qh[2][2], ql[2][2];
#pragma unroll
    for (int mt = 0; mt < 2; ++mt)
#pragma unroll
        for (int kk = 0; kk < 2; ++kk) {
            size_t g = ((size_t)bh * SEQ + q0 + wid * 32 + mt * 16 + lm) * KD
                     + kk * 32 + lq * 8;
            qh[mt][kk] = *(const v8s*)(Qhi + g);
            ql[mt][kk] = *(const v8s*)(Qlo + g);
        }

    v8s vones;
#pragma unroll
    for (int i = 0; i < 8; ++i) vones[i] = (short)0x3F80;   // bf16 1.0

    v4f ctx[2][4], lcol[2];
    float mrun[2][4];
#pragma unroll
    for (int mt = 0; mt < 2; ++mt) {
        lcol[mt] = (v4f){0.f, 0.f, 0.f, 0.f};
#pragma unroll
        for (int r = 0; r < 4; ++r) mrun[mt][r] = -INFINITY;
#pragma unroll
        for (int nt = 0; nt < 4; ++nt)
            ctx[mt][nt] = (v4f){0.f, 0.f, 0.f, 0.f};
    }

    const size_t kbase = (size_t)bh * SEQ * KD;

    for (int t0 = 0; t0 < SEQ; t0 += 64) {
        __syncthreads();
        // ---- stage Khi/Klo (8KB each, contiguous): 2 insts/wave each
        {
            const char* gk1 = (const char*)(Khi + kbase + (size_t)t0 * KD);
            const char* gk2 = (const char*)(Klo + kbase + (size_t)t0 * KD);
            int off = wid * 2048;
#pragma unroll
            for (int i = 0; i < 2; ++i) {
                int o = off + i * 1024;
                gload_lds16(gk1 + o + lane * 16, (char*)sKhi + o);
                gload_lds16(gk2 + o + lane * 16, (char*)sKlo + o);
            }
        }
        // ---- stage Vt rows (128B per hd row): 8 rows/inst, 2 insts/wave
#pragma unroll
        for (int i = 0; i < 2; ++i) {
            int row = wid * 16 + i * 8;
            const char* gv = (const char*)(Vt + ((size_t)bh * KD + row + (lane >> 3)) * SEQ + t0)
                           + (lane & 7) * 16;
            gload_lds16(gv, (char*)sVt + row * 128);
        }
        asm volatile("s_waitcnt vmcnt(0)" ::: "memory");
        __syncthreads();

        // ---- QK^T: 3-term split-bf16, fp32 accum
        v4f sc[2][4];
#pragma unroll
        for (int mt = 0; mt < 2; ++mt)
#pragma unroll
            for (int nt = 0; nt < 4; ++nt)
                sc[mt][nt] = (v4f){0.f, 0.f, 0.f, 0.f};
#pragma unroll
        for (int kk = 0; kk < 2; ++kk) {
#pragma unroll
            for (int nt = 0; nt < 4; ++nt) {
                int key = nt * 16 + lm;
                int blk = (kk * 4 + lq) ^ (key & 7);
                v8s bh16 = *(const v8s*)&sKhi[key * 64 + blk * 8];
                v8s bl16 = *(const v8s*)&sKlo[key * 64 + blk * 8];
#pragma unroll
                for (int mt = 0; mt < 2; ++mt) {
                    sc[mt][nt] = __builtin_amdgcn_mfma_f32_16x16x32_bf16(qh[mt][kk], bh16, sc[mt][nt], 0, 0, 0);
                    sc[mt][nt] = __builtin_amdgcn_mfma_f32_16x16x32_bf16(qh[mt][kk], bl16, sc[mt][nt], 0, 0, 0);
                    sc[mt][nt] = __builtin_amdgcn_mfma_f32_16x16x32_bf16(ql[mt][kk], bh16, sc[mt][nt], 0, 0, 0);
                }
            }
        }

        // ---- online softmax (base-2). C-layout: col=nt*16+lm, row=mt*16+lq*4+r
#pragma unroll
        for (int mt = 0; mt < 2; ++mt) {
#pragma unroll
            for (int r = 0; r < 4; ++r) {
                float v0 = sc[mt][0][r], v1 = sc[mt][1][r];
                float v2 = sc[mt][2][r], v3 = sc[mt][3][r];
                float mx = fmaxf(fmaxf(v0, v1), fmaxf(v2, v3));
                mx = dpp_max16(mx);
                float mold = mrun[mt][r];
                float mnew = fmaxf(mold, mx);
                float alpha = __builtin_amdgcn_exp2f(mold - mnew);
                mrun[mt][r] = mnew;
                float p0 = __builtin_amdgcn_exp2f(v0 - mnew);
                float p1 = __builtin_amdgcn_exp2f(v1 - mnew);
                float p2 = __builtin_amdgcn_exp2f(v2 - mnew);
                float p3 = __builtin_amdgcn_exp2f(v3 - mnew);
                lcol[mt][r] *= alpha;
#pragma unroll
                for (int nt = 0; nt < 4; ++nt)
                    ctx[mt][nt][r] *= alpha;
                int row = wid * 32 + mt * 16 + lq * 4 + r;
                sPs[row * PSTRIDE +  0 + lm] = f2bf(p0);
                sPs[row * PSTRIDE + 16 + lm] = f2bf(p1);
                sPs[row * PSTRIDE + 32 + lm] = f2bf(p2);
                sPs[row * PSTRIDE + 48 + lm] = f2bf(p3);
            }
        }
        // same-wave ds_write -> ds_read (compiler inserts lgkm wait)

        // ---- PV (+ ones column accumulates l)
#pragma unroll
        for (int kk2 = 0; kk2 < 2; ++kk2) {
            v8s a[2];
#pragma unroll
            for (int mt = 0; mt < 2; ++mt)
                a[mt] = *(const v8s*)&sPs[(wid * 32 + mt * 16 + lm) * PSTRIDE + kk2 * 32 + lq * 8];
#pragma unroll
            for (int nt = 0; nt < 4; ++nt) {
                int hd = nt * 16 + lm;
                int blk = (kk2 * 4 + lq) ^ (hd & 7);
                v8s b = *(const v8s*)&sVt[hd * 64 + blk * 8];
#pragma unroll
                for (int mt = 0; mt < 2; ++mt)
                    ctx[mt][nt] = __builtin_amdgcn_mfma_f32_16x16x32_bf16(a[mt], b, ctx[mt][nt], 0, 0, 0);
            }
#pragma unroll
            for (int mt = 0; mt < 2; ++mt)
                lcol[mt] = __builtin_amdgcn_mfma_f32_16x16x32_bf16(a[mt], vones, lcol[mt], 0, 0, 0);
        }
    }

    // ---- epilogue: heads[bb][row][h*64+hd] = ctx / l (bf16)
#pragma unroll
    for (int mt = 0; mt < 2; ++mt)
#pragma unroll
        for (int r = 0; r < 4; ++r) {
            int row = q0 + wid * 32 + mt * 16 + lq * 4 + r;
            float inv = 1.0f / lcol[mt][r];
            u16* dst = headsb + ((size_t)bb * SEQ + row) * EMBED + h * KD;
#pragma unroll
            for (int nt = 0; nt < 4; ++nt)
                dst[nt * 16 + lm] = f2bf(ctx[mt][nt][r] * inv);
        }
}

// ------------------------------------------------------------------
// Kernel: output projection, MFMA bf16 2-term (unchanged).
// ------------------------------------------------------------------
__global__ __launch_bounds__(256)
void out_mfma_kernel(const u16* __restrict__ headsb,
                     const u16* __restrict__ OWth, const u16* __restrict__ OWtl,
                     float* __restrict__ out)
{
    __shared__ u16 sA[128 * 64];
    __shared__ u16 sBh[128 * 64];
    __shared__ u16 sBl[128 * 64];
    const int tid = threadIdx.x;
    const int lane = tid & 63, wid = tid >> 6;
    const int lm = lane & 15, lq = lane >> 4;
    const int wm = wid & 1, wn = wid >> 1;
    const int m0 = blockIdx.y * 128;
    const int n0 = blockIdx.x * 128;

    v4f acc[4][4];
#pragma unroll
    for (int mt = 0; mt < 4; ++mt)
#pragma unroll
        for (int nt = 0; nt < 4; ++nt)
            acc[mt][nt] = (v4f){0.f, 0.f, 0.f, 0.f};

    const int srow = wid * 32 + (lane >> 3);
    const int sblk = (lane & 7) ^ (lane >> 3);

    for (int k0 = 0; k0 < EMBED; k0 += 64) {
        __syncthreads();
#pragma unroll
        for (int i = 0; i < 4; ++i) {
            int row = srow + i * 8;
            size_t gA = (((size_t)(m0 + row)) << 10) + k0 + sblk * 8;
            size_t gB = (((size_t)(n0 + row)) << 10) + k0 + sblk * 8;
            int lo = (wid * 32 + i * 8) * 128;
            gload_lds16((const char*)headsb + gA * 2, (char*)sA + lo);
            gload_lds16((const char*)OWth + gB * 2, (char*)sBh + lo);
            gload_lds16((const char*)OWtl + gB * 2, (char*)sBl + lo);
        }
        asm volatile("s_waitcnt vmcnt(0)" ::: "memory");
        __syncthreads();

#pragma unroll
        for (int kks = 0; kks < 2; ++kks) {
            const int ba = ((kks * 4 + lq) ^ (lm & 7)) * 8;
            v8s ah[4], bh[4], bl[4];
#pragma unroll
            for (int t = 0; t < 4; ++t) {
                int ra = wm * 64 + t * 16 + lm;
                int rb = wn * 64 + t * 16 + lm;
                ah[t] = *(const v8s*)&sA[ra * 64 + ba];
                bh[t] = *(const v8s*)&sBh[rb * 64 + ba];
                bl[t] = *(const v8s*)&sBl[rb * 64 + ba];
            }
#pragma unroll
            for (int mt = 0; mt < 4; ++mt)
#pragma unroll
                for (int nt = 0; nt < 4; ++nt) {
                    acc[mt][nt] = __builtin_amdgcn_mfma_f32_16x16x32_bf16(ah[mt], bh[nt], acc[mt][nt], 0, 0, 0);
                    acc[mt][nt] = __builtin_amdgcn_mfma_f32_16x16x32_bf16(ah[mt], bl[nt], acc[mt][nt], 0, 0, 0);
                }
        }
    }

    const int mrow0 = m0 + wm * 64;
    const int ncol0 = n0 + wn * 64;
#pragma unroll
    for (int mt = 0; mt < 4; ++mt) {
        int sbase = mrow0 + mt * 16 + lq * 4;
#pragma unroll
        for (int nt = 0; nt < 4; ++nt) {
            int n = ncol0 + nt * 16 + lm;
#pragma unroll
            for (int r = 0; r < 4; ++r)
                out[(size_t)(sbase + r) * EMBED + n] = acc[mt][nt][r];
        }
    }
}

// ------------------------------------------------------------------
extern "C" void kernel_launch(void* const* d_in, const int* in_sizes, int n_in,
                              void* d_out, int out_size, void* d_ws, size_t ws_size,
                              hipStream_t stream) {
    const float* x  = (const float*)d_in[0];
    const float* wq = (const float*)d_in[1];
    const float* wk = (const float*)d_in[2];
    const float* wv = (const float*)d_in[3];
    const float* w  = (const float*)d_in[4];
    float* out = (float*)d_out;

    u16* Qhi = (u16*)d_ws;
    u16* Qlo = Qhi + NTOK;
    u16* Khi = Qlo + NTOK;
    u16* Klo = Khi + NTOK;
    u16* Vt  = Klo + NTOK;
    u16* xh  = Vt + NTOK;                 // [8192][1024]
    u16* xl  = xh + NTOK;
    u16* Wth = xl + NTOK;                 // [3072][1024]
    u16* Wtl = Wth + (size_t)3072 * 1024;
    u16* OWth = Wtl + (size_t)3072 * 1024;  // [1024][1024]
    u16* OWtl = OWth + (size_t)1024 * 1024;
    u16* headsb = xh;                     // alias: xh dead after qkv_mfma

    convert_x_kernel<<<8192, 256, 0, stream>>>(x, xh, xl);
    convert_w_kernel<<<3072, 256, 0, stream>>>(wq, wk, wv, Wth, Wtl);
    convert_ow_kernel<<<1024, 256, 0, stream>>>(w, OWth, OWtl);

    dim3 g1(24, 64);
    qkv_mfma_kernel<<<g1, 256, 0, stream>>>(xh, xl, Wth, Wtl, Qhi, Qlo, Khi, Klo, Vt);

    dim3 g2(SEQ / 128, BH);   // 16 x 64, 256-thread blocks (R3 economics)
    attn_kernel<<<g2, 256, 0, stream>>>(Qhi, Qlo, Khi, Klo, Vt, headsb);

    dim3 g3(8, 64);
    out_mfma_kernel<<<g3, 256, 0, stream>>>(headsb, OWth, OWtl, out);
}

// Round 6
// 431.004 us; speedup vs baseline: 1.5137x; 1.1616x over previous
//
#include <hip/hip_runtime.h>
#include <hip/hip_bf16.h>
#include <math.h>

#define EMBED 1024
#define KD 64
#define NH 16
#define SEQ 2048
#define BATCH 4
#define BH (BATCH * NH)     // 64
#define NTOK ((size_t)BH * SEQ * KD)   // 8,388,608

typedef float4 f4;
typedef unsigned short u16;
typedef __attribute__((ext_vector_type(8))) short v8s;   // 8 bf16 (MFMA A/B frag)
typedef __attribute__((ext_vector_type(4))) float v4f;   // MFMA C/D frag

__device__ __forceinline__ u16 f2bf(float f) {
    unsigned u = __float_as_uint(f);
    unsigned r = (u + 0x7fffu + ((u >> 16) & 1u)) >> 16;
    return (u16)r;
}
__device__ __forceinline__ float bf2f(u16 h) {
    return __uint_as_float(((unsigned)h) << 16);
}

// async global->LDS, 16B/lane. LDS dest = wave-uniform base + lane*16.
__device__ __forceinline__ void gload_lds16(const void* g, void* l) {
    __builtin_amdgcn_global_load_lds(
        (const __attribute__((address_space(1))) unsigned int*)g,
        (__attribute__((address_space(3))) unsigned int*)l, 16, 0, 0);
}

// ------------------------------------------------------------------
// Fused converter: blocks [0,8192) -> x split; [8192,11264) -> qkv W
// (transposed, Q scaled by 0.125*log2e); [11264,12288) -> out W.
// ------------------------------------------------------------------
__global__ __launch_bounds__(256)
void convert_all_kernel(const float* __restrict__ x,
                        const float* __restrict__ wq, const float* __restrict__ wk,
                        const float* __restrict__ wv, const float* __restrict__ w,
                        u16* __restrict__ xh, u16* __restrict__ xl,
                        u16* __restrict__ Wth, u16* __restrict__ Wtl,
                        u16* __restrict__ OWth, u16* __restrict__ OWtl)
{
    int b = blockIdx.x;
    if (b < 8192) {
        size_t i = ((size_t)b * 256 + threadIdx.x) * 4;
        f4 v = *(const f4*)(x + i);
        u16 h0 = f2bf(v.x), h1 = f2bf(v.y), h2 = f2bf(v.z), h3 = f2bf(v.w);
        u16 l0 = f2bf(v.x - bf2f(h0)), l1 = f2bf(v.y - bf2f(h1));
        u16 l2 = f2bf(v.z - bf2f(h2)), l3 = f2bf(v.w - bf2f(h3));
        uint2 H, L;
        H.x = (unsigned)h0 | ((unsigned)h1 << 16);
        H.y = (unsigned)h2 | ((unsigned)h3 << 16);
        L.x = (unsigned)l0 | ((unsigned)l1 << 16);
        L.y = (unsigned)l2 | ((unsigned)l3 << 16);
        *(uint2*)(xh + i) = H;
        *(uint2*)(xl + i) = L;
    } else if (b < 8192 + 3072) {
        int n = b - 8192;                     // 0..3071
        int mat = n >> 10, nin = n & 1023, h = nin >> 6, c = nin & 63;
        const float* __restrict__ ws = (mat == 0) ? wq : (mat == 1) ? wk : wv;
        float sc = (mat == 0) ? (0.125f * 1.4426950408889634f) : 1.0f;
        for (int d = threadIdx.x; d < EMBED; d += 256) {
            float f = ws[((size_t)h * EMBED + d) * KD + c] * sc;
            u16 hi = f2bf(f);
            u16 lo = f2bf(f - bf2f(hi));
            Wth[(size_t)n * EMBED + d] = hi;
            Wtl[(size_t)n * EMBED + d] = lo;
        }
    } else {
        int n = b - 11264;                    // 0..1023
        for (int k = threadIdx.x; k < EMBED; k += 256) {
            float f = w[(size_t)k * EMBED + n];
            u16 hi = f2bf(f);
            u16 lo = f2bf(f - bf2f(hi));
            OWth[(size_t)n * EMBED + k] = hi;
            OWtl[(size_t)n * EMBED + k] = lo;
        }
    }
}

// ------------------------------------------------------------------
// Kernel: QKV projection, MFMA bf16 (unchanged from R5).
// ------------------------------------------------------------------
__global__ __launch_bounds__(256)
void qkv_mfma_kernel(const u16* __restrict__ xh, const u16* __restrict__ xl,
                     const u16* __restrict__ Wth, const u16* __restrict__ Wtl,
                     u16* __restrict__ Qhi, u16* __restrict__ Qlo,
                     u16* __restrict__ Khi, u16* __restrict__ Klo,
                     u16* __restrict__ Vt)
{
    __shared__ u16 sAh[128 * 64];
    __shared__ u16 sAl[128 * 64];
    __shared__ u16 sBh[128 * 64];
    __shared__ u16 sBl[128 * 64];
    const int tid = threadIdx.x;
    const int lane = tid & 63, wid = tid >> 6;
    const int lm = lane & 15, lq = lane >> 4;
    const int wm = wid & 1, wn = wid >> 1;
    const int m0 = blockIdx.y * 128;
    const int n0 = blockIdx.x * 128;
    const bool three = (n0 < 2048);

    v4f acc[4][4];
#pragma unroll
    for (int mt = 0; mt < 4; ++mt)
#pragma unroll
        for (int nt = 0; nt < 4; ++nt)
            acc[mt][nt] = (v4f){0.f, 0.f, 0.f, 0.f};

    const int srow = wid * 32 + (lane >> 3);
    const int sblk = (lane & 7) ^ (lane >> 3);

    for (int k0 = 0; k0 < EMBED; k0 += 64) {
        __syncthreads();
#pragma unroll
        for (int i = 0; i < 4; ++i) {
            int row = srow + i * 8;
            size_t gA = (((size_t)(m0 + row)) << 10) + k0 + sblk * 8;
            size_t gB = (((size_t)(n0 + row)) << 10) + k0 + sblk * 8;
            int lo = (wid * 32 + i * 8) * 128;
            gload_lds16((const char*)xh + gA * 2, (char*)sAh + lo);
            gload_lds16((const char*)Wth + gB * 2, (char*)sBh + lo);
            if (three) {
                gload_lds16((const char*)xl + gA * 2, (char*)sAl + lo);
                gload_lds16((const char*)Wtl + gB * 2, (char*)sBl + lo);
            }
        }
        asm volatile("s_waitcnt vmcnt(0)" ::: "memory");
        __syncthreads();

#pragma unroll
        for (int kks = 0; kks < 2; ++kks) {
            v8s ah[4], bh[4];
            const int ba = ((kks * 4 + lq) ^ (lm & 7)) * 8;
#pragma unroll
            for (int t = 0; t < 4; ++t) {
                int ra = wm * 64 + t * 16 + lm;
                int rb = wn * 64 + t * 16 + lm;
                ah[t] = *(const v8s*)&sAh[ra * 64 + ba];
                bh[t] = *(const v8s*)&sBh[rb * 64 + ba];
            }
            if (three) {
                v8s al[4], bl[4];
#pragma unroll
                for (int t = 0; t < 4; ++t) {
                    int ra = wm * 64 + t * 16 + lm;
                    int rb = wn * 64 + t * 16 + lm;
                    al[t] = *(const v8s*)&sAl[ra * 64 + ba];
                    bl[t] = *(const v8s*)&sBl[rb * 64 + ba];
                }
#pragma unroll
                for (int mt = 0; mt < 4; ++mt)
#pragma unroll
                    for (int nt = 0; nt < 4; ++nt) {
                        acc[mt][nt] = __builtin_amdgcn_mfma_f32_16x16x32_bf16(ah[mt], bh[nt], acc[mt][nt], 0, 0, 0);
                        acc[mt][nt] = __builtin_amdgcn_mfma_f32_16x16x32_bf16(ah[mt], bl[nt], acc[mt][nt], 0, 0, 0);
                        acc[mt][nt] = __builtin_amdgcn_mfma_f32_16x16x32_bf16(al[mt], bh[nt], acc[mt][nt], 0, 0, 0);
                    }
            } else {
#pragma unroll
                for (int mt = 0; mt < 4; ++mt)
#pragma unroll
                    for (int nt = 0; nt < 4; ++nt)
                        acc[mt][nt] = __builtin_amdgcn_mfma_f32_16x16x32_bf16(ah[mt], bh[nt], acc[mt][nt], 0, 0, 0);
            }
        }
    }

    const int mrow0 = m0 + wm * 64;
    const int ncol0 = n0 + wn * 64;
    if (!three) {
#pragma unroll
        for (int mt = 0; mt < 4; ++mt) {
            int sbase = mrow0 + mt * 16 + lq * 4;
            int bb = sbase >> 11, s = sbase & 2047;
#pragma unroll
            for (int nt = 0; nt < 4; ++nt) {
                int nin = (ncol0 + nt * 16 + lm) & 1023;
                int h = nin >> 6, cc = nin & 63;
                int bh_ = bb * NH + h;
                size_t a = ((size_t)bh_ * KD + cc) * SEQ
                         + (size_t)(((((s >> 3) ^ (cc & 7)) << 3)) | (s & 7));
                uint2 u;
                u.x = (unsigned)f2bf(acc[mt][nt][0]) | ((unsigned)f2bf(acc[mt][nt][1]) << 16);
                u.y = (unsigned)f2bf(acc[mt][nt][2]) | ((unsigned)f2bf(acc[mt][nt][3]) << 16);
                *(uint2*)(Vt + a) = u;
            }
        }
    } else {
        const bool isQ = (n0 < 1024);
#pragma unroll
        for (int mt = 0; mt < 4; ++mt) {
            int sbase = mrow0 + mt * 16 + lq * 4;
            int bb = sbase >> 11, sB = sbase & 2047;
#pragma unroll
            for (int nt = 0; nt < 4; ++nt) {
                int nin = (ncol0 + nt * 16 + lm) & 1023;
                int h = nin >> 6, cc = nin & 63;
                int bh_ = bb * NH + h;
#pragma unroll
                for (int r = 0; r < 4; ++r) {
                    int s = sB + r;
                    float f = acc[mt][nt][r];
                    u16 hi = f2bf(f);
                    u16 lo = f2bf(f - bf2f(hi));
                    if (isQ) {
                        size_t a = ((size_t)bh_ * SEQ + s) * KD + cc;
                        Qhi[a] = hi;
                        Qlo[a] = lo;
                    } else {
                        int ccp = ((((cc >> 3) ^ (s & 7)) << 3) | (cc & 7));
                        size_t a = ((size_t)bh_ * SEQ + s) * KD + ccp;
                        Khi[a] = hi;
                        Klo[a] = lo;
                    }
                }
            }
        }
    }
}

// ------------------------------------------------------------------
// Kernel: flash attention, transposed-score variant.
// Scores computed as K·Q^T (A=K from LDS, B=Q resident regs — same
// addresses/regs as before, operands swapped). C-layout then gives
// col=q-row, rows=keys: per-lane max is 15 in-lane fmax + 2 shfl_xor;
// P quads are 4 consecutive keys -> v_perm pack + ds_write_b64.
// P stored as truncated bf16 (bias cancels in ctx/l via ones-MFMA).
// alpha routed to ctx-orientation rows via 4 precomputed ds_bpermute.
// ------------------------------------------------------------------
#define PSTRIDE 72   // u16; 144B rows

__global__ __launch_bounds__(256)
void attn_kernel(const u16* __restrict__ Qhi, const u16* __restrict__ Qlo,
                 const u16* __restrict__ Khi, const u16* __restrict__ Klo,
                 const u16* __restrict__ Vt,  u16* __restrict__ headsb)
{
    __shared__ u16 sKhi[64 * 64];
    __shared__ u16 sKlo[64 * 64];
    __shared__ u16 sVt[64 * 64];
    __shared__ u16 sPs[128 * PSTRIDE];

    const int tid = threadIdx.x;
    const int lane = tid & 63, wid = tid >> 6;
    const int lm = lane & 15, lq = lane >> 4;
    const int q0 = blockIdx.x * 128;
    const int bh = blockIdx.y;
    const int bb = bh >> 4, h = bh & 15;

    // Q fragments resident: q-rows q0 + wid*32 + qt*16 + lm
    v8s qh[2][2], ql[2][2];
#pragma unroll
    for (int qt = 0; qt < 2; ++qt)
#pragma unroll
        for (int kk = 0; kk < 2; ++kk) {
            size_t g = ((size_t)bh * SEQ + q0 + wid * 32 + qt * 16 + lm) * KD
                     + kk * 32 + lq * 8;
            qh[qt][kk] = *(const v8s*)(Qhi + g);
            ql[qt][kk] = *(const v8s*)(Qlo + g);
        }

    v8s vones;
#pragma unroll
    for (int i = 0; i < 8; ++i) vones[i] = (short)0x3F80;   // bf16 1.0

    // bpermute source-lane addrs: alpha for ctx row lq*4+r lives at lane
    // (same lq group) with lm = lq*4+r
    int bpaddr[4];
#pragma unroll
    for (int r = 0; r < 4; ++r)
        bpaddr[r] = (((lane & 48) | (lq * 4 + r)) << 2);

    v4f ctx[2][4], lcol[2];
    float mrun[2];
#pragma unroll
    for (int qt = 0; qt < 2; ++qt) {
        lcol[qt] = (v4f){0.f, 0.f, 0.f, 0.f};
        mrun[qt] = -INFINITY;
#pragma unroll
        for (int nt = 0; nt < 4; ++nt)
            ctx[qt][nt] = (v4f){0.f, 0.f, 0.f, 0.f};
    }

    const size_t kbase = (size_t)bh * SEQ * KD;

    for (int t0 = 0; t0 < SEQ; t0 += 64) {
        __syncthreads();
        // ---- stage Khi/Klo (8KB each, contiguous)
        {
            const char* gk1 = (const char*)(Khi + kbase + (size_t)t0 * KD);
            const char* gk2 = (const char*)(Klo + kbase + (size_t)t0 * KD);
            int off = wid * 2048;
#pragma unroll
            for (int i = 0; i < 2; ++i) {
                int o = off + i * 1024;
                gload_lds16(gk1 + o + lane * 16, (char*)sKhi + o);
                gload_lds16(gk2 + o + lane * 16, (char*)sKlo + o);
            }
        }
        // ---- stage Vt rows (128B per hd row)
#pragma unroll
        for (int i = 0; i < 2; ++i) {
            int row = wid * 16 + i * 8;
            const char* gv = (const char*)(Vt + ((size_t)bh * KD + row + (lane >> 3)) * SEQ + t0)
                           + (lane & 7) * 16;
            gload_lds16(gv, (char*)sVt + row * 128);
        }
        asm volatile("s_waitcnt vmcnt(0)" ::: "memory");
        __syncthreads();

        // ---- scores = K·Q^T (transposed): sc[kt][qt], rows=keys, cols=qrows
        v4f sc[4][2];
#pragma unroll
        for (int kt = 0; kt < 4; ++kt)
#pragma unroll
            for (int qt = 0; qt < 2; ++qt)
                sc[kt][qt] = (v4f){0.f, 0.f, 0.f, 0.f};
#pragma unroll
        for (int kk = 0; kk < 2; ++kk) {
#pragma unroll
            for (int kt = 0; kt < 4; ++kt) {
                int key = kt * 16 + lm;
                int blk = (kk * 4 + lq) ^ (key & 7);
                v8s kh16 = *(const v8s*)&sKhi[key * 64 + blk * 8];
                v8s kl16 = *(const v8s*)&sKlo[key * 64 + blk * 8];
#pragma unroll
                for (int qt = 0; qt < 2; ++qt) {
                    sc[kt][qt] = __builtin_amdgcn_mfma_f32_16x16x32_bf16(kh16, qh[qt][kk], sc[kt][qt], 0, 0, 0);
                    sc[kt][qt] = __builtin_amdgcn_mfma_f32_16x16x32_bf16(kl16, qh[qt][kk], sc[kt][qt], 0, 0, 0);
                    sc[kt][qt] = __builtin_amdgcn_mfma_f32_16x16x32_bf16(kh16, ql[qt][kk], sc[kt][qt], 0, 0, 0);
                }
            }
        }

        // ---- online softmax (base-2): per lane, one q-row (lm) per qt;
        // lane's 16 values = keys kt*16 + lq*4 + r.
        float aq[2];
#pragma unroll
        for (int qt = 0; qt < 2; ++qt) {
            float m0v = fmaxf(fmaxf(sc[0][qt][0], sc[0][qt][1]), fmaxf(sc[0][qt][2], sc[0][qt][3]));
            float m1v = fmaxf(fmaxf(sc[1][qt][0], sc[1][qt][1]), fmaxf(sc[1][qt][2], sc[1][qt][3]));
            float m2v = fmaxf(fmaxf(sc[2][qt][0], sc[2][qt][1]), fmaxf(sc[2][qt][2], sc[2][qt][3]));
            float m3v = fmaxf(fmaxf(sc[3][qt][0], sc[3][qt][1]), fmaxf(sc[3][qt][2], sc[3][qt][3]));
            float mx = fmaxf(fmaxf(m0v, m1v), fmaxf(m2v, m3v));
            mx = fmaxf(mx, __shfl_xor(mx, 16));
            mx = fmaxf(mx, __shfl_xor(mx, 32));
            float mold = mrun[qt];
            float mnew = fmaxf(mold, mx);
            aq[qt] = __builtin_amdgcn_exp2f(mold - mnew);
            mrun[qt] = mnew;
            // p, truncate-pack, b64 write: 4 consecutive keys per quad
            u16* pbase = &sPs[(wid * 32 + qt * 16 + lm) * PSTRIDE];
#pragma unroll
            for (int kt = 0; kt < 4; ++kt) {
                unsigned u0 = __float_as_uint(__builtin_amdgcn_exp2f(sc[kt][qt][0] - mnew));
                unsigned u1 = __float_as_uint(__builtin_amdgcn_exp2f(sc[kt][qt][1] - mnew));
                unsigned u2 = __float_as_uint(__builtin_amdgcn_exp2f(sc[kt][qt][2] - mnew));
                unsigned u3 = __float_as_uint(__builtin_amdgcn_exp2f(sc[kt][qt][3] - mnew));
                uint2 pk;
                pk.x = __builtin_amdgcn_perm(u1, u0, 0x07060302);  // [bf(p1)|bf(p0)]
                pk.y = __builtin_amdgcn_perm(u3, u2, 0x07060302);
                *(uint2*)&pbase[kt * 16 + lq * 4] = pk;
            }
        }

        // ---- rescale ctx/lcol: route alpha to ctx-orientation rows
#pragma unroll
        for (int qt = 0; qt < 2; ++qt) {
#pragma unroll
            for (int r = 0; r < 4; ++r) {
                float ar = __uint_as_float(
                    __builtin_amdgcn_ds_bpermute(bpaddr[r], __float_as_uint(aq[qt])));
                lcol[qt][r] *= ar;
#pragma unroll
                for (int nt = 0; nt < 4; ++nt)
                    ctx[qt][nt][r] *= ar;
            }
        }
        // same-wave ds_write -> ds_read (compiler inserts lgkm wait)

        // ---- PV (+ ones column accumulates l)
#pragma unroll
        for (int kk2 = 0; kk2 < 2; ++kk2) {
            v8s a[2];
#pragma unroll
            for (int qt = 0; qt < 2; ++qt)
                a[qt] = *(const v8s*)&sPs[(wid * 32 + qt * 16 + lm) * PSTRIDE + kk2 * 32 + lq * 8];
#pragma unroll
            for (int nt = 0; nt < 4; ++nt) {
                int hd = nt * 16 + lm;
                int blk = (kk2 * 4 + lq) ^ (hd & 7);
                v8s b = *(const v8s*)&sVt[hd * 64 + blk * 8];
#pragma unroll
                for (int qt = 0; qt < 2; ++qt)
                    ctx[qt][nt] = __builtin_amdgcn_mfma_f32_16x16x32_bf16(a[qt], b, ctx[qt][nt], 0, 0, 0);
            }
#pragma unroll
            for (int qt = 0; qt < 2; ++qt)
                lcol[qt] = __builtin_amdgcn_mfma_f32_16x16x32_bf16(a[qt], vones, lcol[qt], 0, 0, 0);
        }
    }

    // ---- epilogue: heads[bb][row][h*64+hd] = ctx / l (bf16)
#pragma unroll
    for (int qt = 0; qt < 2; ++qt)
#pragma unroll
        for (int r = 0; r < 4; ++r) {
            int row = q0 + wid * 32 + qt * 16 + lq * 4 + r;
            float inv = 1.0f / lcol[qt][r];
            u16* dst = headsb + ((size_t)bb * SEQ + row) * EMBED + h * KD;
#pragma unroll
            for (int nt = 0; nt < 4; ++nt)
                dst[nt * 16 + lm] = f2bf(ctx[qt][nt][r] * inv);
        }
}

// ------------------------------------------------------------------
// Kernel: output projection, MFMA bf16 2-term (unchanged).
// ------------------------------------------------------------------
__global__ __launch_bounds__(256)
void out_mfma_kernel(const u16* __restrict__ headsb,
                     const u16* __restrict__ OWth, const u16* __restrict__ OWtl,
                     float* __restrict__ out)
{
    __shared__ u16 sA[128 * 64];
    __shared__ u16 sBh[128 * 64];
    __shared__ u16 sBl[128 * 64];
    const int tid = threadIdx.x;
    const int lane = tid & 63, wid = tid >> 6;
    const int lm = lane & 15, lq = lane >> 4;
    const int wm = wid & 1, wn = wid >> 1;
    const int m0 = blockIdx.y * 128;
    const int n0 = blockIdx.x * 128;

    v4f acc[4][4];
#pragma unroll
    for (int mt = 0; mt < 4; ++mt)
#pragma unroll
        for (int nt = 0; nt < 4; ++nt)
            acc[mt][nt] = (v4f){0.f, 0.f, 0.f, 0.f};

    const int srow = wid * 32 + (lane >> 3);
    const int sblk = (lane & 7) ^ (lane >> 3);

    for (int k0 = 0; k0 < EMBED; k0 += 64) {
        __syncthreads();
#pragma unroll
        for (int i = 0; i < 4; ++i) {
            int row = srow + i * 8;
            size_t gA = (((size_t)(m0 + row)) << 10) + k0 + sblk * 8;
            size_t gB = (((size_t)(n0 + row)) << 10) + k0 + sblk * 8;
            int lo = (wid * 32 + i * 8) * 128;
            gload_lds16((const char*)headsb + gA * 2, (char*)sA + lo);
            gload_lds16((const char*)OWth + gB * 2, (char*)sBh + lo);
            gload_lds16((const char*)OWtl + gB * 2, (char*)sBl + lo);
        }
        asm volatile("s_waitcnt vmcnt(0)" ::: "memory");
        __syncthreads();

#pragma unroll
        for (int kks = 0; kks < 2; ++kks) {
            const int ba = ((kks * 4 + lq) ^ (lm & 7)) * 8;
            v8s ah[4], bh[4], bl[4];
#pragma unroll
            for (int t = 0; t < 4; ++t) {
                int ra = wm * 64 + t * 16 + lm;
                int rb = wn * 64 + t * 16 + lm;
                ah[t] = *(const v8s*)&sA[ra * 64 + ba];
                bh[t] = *(const v8s*)&sBh[rb * 64 + ba];
                bl[t] = *(const v8s*)&sBl[rb * 64 + ba];
            }
#pragma unroll
            for (int mt = 0; mt < 4; ++mt)
#pragma unroll
                for (int nt = 0; nt < 4; ++nt) {
                    acc[mt][nt] = __builtin_amdgcn_mfma_f32_16x16x32_bf16(ah[mt], bh[nt], acc[mt][nt], 0, 0, 0);
                    acc[mt][nt] = __builtin_amdgcn_mfma_f32_16x16x32_bf16(ah[mt], bl[nt], acc[mt][nt], 0, 0, 0);
                }
        }
    }

    const int mrow0 = m0 + wm * 64;
    const int ncol0 = n0 + wn * 64;
#pragma unroll
    for (int mt = 0; mt < 4; ++mt) {
        int sbase = mrow0 + mt * 16 + lq * 4;
#pragma unroll
        for (int nt = 0; nt < 4; ++nt) {
            int n = ncol0 + nt * 16 + lm;
#pragma unroll
            for (int r = 0; r < 4; ++r)
                out[(size_t)(sbase + r) * EMBED + n] = acc[mt][nt][r];
        }
    }
}

// ------------------------------------------------------------------
extern "C" void kernel_launch(void* const* d_in, const int* in_sizes, int n_in,
                              void* d_out, int out_size, void* d_ws, size_t ws_size,
                              hipStream_t stream) {
    const float* x  = (const float*)d_in[0];
    const float* wq = (const float*)d_in[1];
    const float* wk = (const float*)d_in[2];
    const float* wv = (const float*)d_in[3];
    const float* w  = (const float*)d_in[4];
    float* out = (float*)d_out;

    u16* Qhi = (u16*)d_ws;
    u16* Qlo = Qhi + NTOK;
    u16* Khi = Qlo + NTOK;
    u16* Klo = Khi + NTOK;
    u16* Vt  = Klo + NTOK;
    u16* xh  = Vt + NTOK;                 // [8192][1024]
    u16* xl  = xh + NTOK;
    u16* Wth = xl + NTOK;                 // [3072][1024]
    u16* Wtl = Wth + (size_t)3072 * 1024;
    u16* OWth = Wtl + (size_t)3072 * 1024;  // [1024][1024]
    u16* OWtl = OWth + (size_t)1024 * 1024;
    u16* headsb = xh;                     // alias: xh dead after qkv_mfma

    convert_all_kernel<<<12288, 256, 0, stream>>>(x, wq, wk, wv, w,
                                                  xh, xl, Wth, Wtl, OWth, OWtl);

    dim3 g1(24, 64);
    qkv_mfma_kernel<<<g1, 256, 0, stream>>>(xh, xl, Wth, Wtl, Qhi, Qlo, Khi, Klo, Vt);

    dim3 g2(SEQ / 128, BH);   // 16 x 64, 256-thread blocks
    attn_kernel<<<g2, 256, 0, stream>>>(Qhi, Qlo, Khi, Klo, Vt, headsb);

    dim3 g3(8, 64);
    out_mfma_kernel<<<g3, 256, 0, stream>>>(headsb, OWth, OWtl, out);
}